// Round 21
// baseline (221.096 us; speedup 1.0000x reference)
//
#include <hip/hip_runtime.h>
#include <hip/hip_bf16.h>

#define BB 64
#define TT 512
#define FF 1024
#define KK 64
#define EMSZ ((size_t)BB * TT * KK)

typedef unsigned char uchar;
typedef float float2v __attribute__((ext_vector_type(2)));

// ---------------- Emission v3: 8x8 microtile, f-split x4 (r20, ~51us) ----------------
#define E3T 32
#define E3PA 260
#define E3PB 68

__global__ __launch_bounds__(256)
void emission3_kernel(const float* __restrict__ X, const float* __restrict__ W,
                      float* __restrict__ part)
{
    __shared__ float As[E3T][E3PA];
    __shared__ float Bs[E3T][E3PB];
    const int tid = threadIdx.x;
    const int bid = blockIdx.x;
    const int fs = bid & 3;
    const int rb = bid >> 2;
    const int row0 = rb * 256;
    const int fb = fs * 256;
    const int rg = tid >> 3;
    const int cg = tid & 7;
    const int r_base = rg * 8;
    const int c_base = cg * 8;

    float acc[8][8];
#pragma unroll
    for (int i = 0; i < 8; ++i)
#pragma unroll
        for (int j = 0; j < 8; ++j) acc[i][j] = 0.f;

    for (int ft = 0; ft < 256; ft += E3T) {
#pragma unroll
        for (int p = 0; p < 8; ++p) {
            const int idx = p * 256 + tid;
            const int row = idx >> 3;
            const int fq = idx & 7;
            const float4 a = *(const float4*)(X + (size_t)(row0 + row) * FF + fb + ft + fq * 4);
            As[fq * 4 + 0][row] = a.x;
            As[fq * 4 + 1][row] = a.y;
            As[fq * 4 + 2][row] = a.z;
            As[fq * 4 + 3][row] = a.w;
        }
#pragma unroll
        for (int p = 0; p < 2; ++p) {
            const int idx = p * 256 + tid;
            const int c = idx >> 3;
            const int fq = idx & 7;
            const float4 w = *(const float4*)(W + (size_t)c * FF + fb + ft + fq * 4);
            Bs[fq * 4 + 0][c] = w.x;
            Bs[fq * 4 + 1][c] = w.y;
            Bs[fq * 4 + 2][c] = w.z;
            Bs[fq * 4 + 3][c] = w.w;
        }
        __syncthreads();
#pragma unroll
        for (int f = 0; f < E3T; ++f) {
            const float4 a0 = *(const float4*)&As[f][r_base];
            const float4 a1 = *(const float4*)&As[f][r_base + 4];
            const float4 b0 = *(const float4*)&Bs[f][c_base];
            const float4 b1 = *(const float4*)&Bs[f][c_base + 4];
            const float av[8] = { a0.x, a0.y, a0.z, a0.w, a1.x, a1.y, a1.z, a1.w };
            const float bv[8] = { b0.x, b0.y, b0.z, b0.w, b1.x, b1.y, b1.z, b1.w };
#pragma unroll
            for (int i = 0; i < 8; ++i)
#pragma unroll
                for (int j = 0; j < 8; ++j)
                    acc[i][j] = fmaf(av[i], bv[j], acc[i][j]);
        }
        __syncthreads();
    }

    float* pp = part + (size_t)fs * EMSZ;
#pragma unroll
    for (int i = 0; i < 8; ++i) {
        float4 o0, o1;
        o0.x = acc[i][0]; o0.y = acc[i][1]; o0.z = acc[i][2]; o0.w = acc[i][3];
        o1.x = acc[i][4]; o1.y = acc[i][5]; o1.z = acc[i][6]; o1.w = acc[i][7];
        float* op = pp + (size_t)(row0 + r_base + i) * KK + c_base;
        *(float4*)(op + 0) = o0;
        *(float4*)(op + 4) = o1;
    }
}

__global__ __launch_bounds__(256)
void emadd_kernel(const float* __restrict__ part, const float* __restrict__ bias,
                  float* __restrict__ em)
{
    const size_t i = (size_t)blockIdx.x * 256 + threadIdx.x;
    const float4* p0 = (const float4*)part;
    const float4* p1 = (const float4*)(part + EMSZ);
    const float4* p2 = (const float4*)(part + 2 * EMSZ);
    const float4* p3 = (const float4*)(part + 3 * EMSZ);
    const float4 a = p0[i], b = p1[i], c = p2[i], d = p3[i];
    const float4 bv = *(const float4*)(bias + ((int)(i & 15)) * 4);
    float4 o;
    o.x = (((a.x + b.x) + c.x) + d.x) + bv.x;
    o.y = (((a.y + b.y) + c.y) + d.y) + bv.y;
    o.z = (((a.z + b.z) + c.z) + d.z) + bv.z;
    o.w = (((a.w + b.w) + c.w) + d.w) + bv.w;
    ((float4*)em)[i] = o;
}

// ---------------- Emission v1 (fallback, measured ~84us 7x) ----------------
#define BM 64
#define BF 64
#define LDA 68

__global__ __launch_bounds__(256)
void emission_kernel(const float* __restrict__ X, const float* __restrict__ W,
                     const float* __restrict__ bias, float* __restrict__ em)
{
    __shared__ float As[BF][LDA];
    __shared__ float Bs[BF][LDA];
    const int tid = threadIdx.x;
    const int row0 = blockIdx.x * BM;
    const int tm = tid & 15;
    const int tn = tid >> 4;
    const int lq = tid & 15;
    const int lr = tid >> 4;

    float acc[4][4];
#pragma unroll
    for (int i = 0; i < 4; ++i)
#pragma unroll
        for (int jj = 0; jj < 4; ++jj) acc[i][jj] = 0.f;

    for (int f0 = 0; f0 < FF; f0 += BF) {
#pragma unroll
        for (int p = 0; p < 4; ++p) {
            const int r = p * 16 + lr;
            float4 a = *(const float4*)(X + (size_t)(row0 + r) * FF + f0 + lq * 4);
            As[lq * 4 + 0][r] = a.x;
            As[lq * 4 + 1][r] = a.y;
            As[lq * 4 + 2][r] = a.z;
            As[lq * 4 + 3][r] = a.w;
            float4 w = *(const float4*)(W + (size_t)r * FF + f0 + lq * 4);
            Bs[lq * 4 + 0][r] = w.x;
            Bs[lq * 4 + 1][r] = w.y;
            Bs[lq * 4 + 2][r] = w.z;
            Bs[lq * 4 + 3][r] = w.w;
        }
        __syncthreads();
#pragma unroll
        for (int f = 0; f < BF; ++f) {
            float4 a = *(const float4*)&As[f][tm * 4];
            float4 b = *(const float4*)&Bs[f][tn * 4];
            acc[0][0] += a.x * b.x; acc[0][1] += a.x * b.y; acc[0][2] += a.x * b.z; acc[0][3] += a.x * b.w;
            acc[1][0] += a.y * b.x; acc[1][1] += a.y * b.y; acc[1][2] += a.y * b.z; acc[1][3] += a.y * b.w;
            acc[2][0] += a.z * b.x; acc[2][1] += a.z * b.y; acc[2][2] += a.z * b.z; acc[2][3] += a.z * b.w;
            acc[3][0] += a.w * b.x; acc[3][1] += a.w * b.y; acc[3][2] += a.w * b.z; acc[3][3] += a.w * b.w;
        }
        __syncthreads();
    }

    const float4 b4 = *(const float4*)(bias + tn * 4);
#pragma unroll
    for (int i = 0; i < 4; ++i) {
        float4 o;
        o.x = acc[i][0] + b4.x;
        o.y = acc[i][1] + b4.y;
        o.z = acc[i][2] + b4.z;
        o.w = acc[i][3] + b4.w;
        *(float4*)(em + (size_t)(row0 + tm * 4 + i) * KK + tn * 4) = o;
    }
}

// ---------------- Forward: value-only, LDS-broadcast + packed adds, unroll-8 ----------------
#define VSTEP(EV, TIDX) do {                                                   \
    const float2v* sp2 = (const float2v*)&sbuf[(TIDX) & 1][0];                 \
    float m_;                                                                  \
    _Pragma("unroll")                                                          \
    for (int c = 0; c < 8; ++c) {                                              \
        const float2v p0 = sp2[c * 4 + 0] + tc2[c * 4 + 0];                    \
        const float2v p1 = sp2[c * 4 + 1] + tc2[c * 4 + 1];                    \
        const float2v p2 = sp2[c * 4 + 2] + tc2[c * 4 + 2];                    \
        const float2v p3 = sp2[c * 4 + 3] + tc2[c * 4 + 3];                    \
        const float ma = fmaxf(fmaxf(p0.x, p0.y), p1.x);   /* v_max3 */        \
        const float mb = fmaxf(fmaxf(p1.y, p2.x), p2.y);                       \
        const float mc = fmaxf(fmaxf(p3.x, p3.y), ma);                         \
        const float w_ = fmaxf(mb, mc);                                        \
        m_ = (c == 0) ? w_ : fmaxf(m_, w_);                                    \
    }                                                                          \
    score = m_ + (EV);                                                         \
    sbuf[((TIDX) + 1) & 1][j] = score;                                         \
    sb[(size_t)(TIDX) * KK + j] = score;                                       \
} while (0)

#define EPF(D) emb[(size_t)(((D) < TT) ? (D) : (TT - 1)) * KK + j]
#define RLANE(I) __uint_as_float((unsigned)__builtin_amdgcn_readlane((int)__float_as_uint(score), (I)))

__global__ __launch_bounds__(64)
__attribute__((amdgpu_waves_per_eu(1, 1)))
void viterbi_fwd(const float* __restrict__ em, const void* __restrict__ maskp,
                 const float* __restrict__ startT, const float* __restrict__ endT,
                 const float* __restrict__ trans, float* __restrict__ shist,
                 int* __restrict__ btarr)
{
    __shared__ float sbuf[2][KK];

    const int b = blockIdx.x;
    const int j = threadIdx.x;

    const uchar* m8 = (const uchar*)maskp;
    const int* m32 = (const int*)maskp;
    const bool u8m = (m8[1] != 0);

    int myc;
    if (u8m) {
        const uint2 mv = *(const uint2*)(m8 + (size_t)b * TT + j * 8);
        const unsigned s4 = (mv.x & 0x01010101u) + (mv.y & 0x01010101u);
        myc = (int)((s4 * 0x01010101u) >> 24);
    } else {
        const int* mp = m32 + (size_t)b * TT + j * 8;
        const int4 a = *(const int4*)mp;
        const int4 c = *(const int4*)(mp + 4);
        myc = (a.x != 0) + (a.y != 0) + (a.z != 0) + (a.w != 0)
            + (c.x != 0) + (c.y != 0) + (c.z != 0) + (c.w != 0);
    }
#pragma unroll
    for (int o = 1; o < 64; o <<= 1) myc += __shfl_xor(myc, o, 64);
    const int len = myc;

    float2v tc2[32];
#pragma unroll
    for (int i = 0; i < 32; ++i) {
        tc2[i].x = trans[(2 * i) * KK + j];
        tc2[i].y = trans[(2 * i + 1) * KK + j];
    }
#pragma unroll
    for (int i = 0; i < 32; ++i) asm volatile("" : "+v"(tc2[i]));

    const float* emb = em + (size_t)b * TT * KK;
    float* sb = shist + (size_t)b * TT * KK;

    float score = startT[j] + emb[j];
    sb[j] = score;
    sbuf[1][j] = score;

    float eA = EPF(1), eB = EPF(2), eC = EPF(3), eD = EPF(4);
    float eE = EPF(5), eF = EPF(6), eG = EPF(7), eH = EPF(8);

    int t = 1;
    for (; t + 7 < len; t += 8) {
        VSTEP(eA, t);     eA = EPF(t + 8);
        VSTEP(eB, t + 1); eB = EPF(t + 9);
        VSTEP(eC, t + 2); eC = EPF(t + 10);
        VSTEP(eD, t + 3); eD = EPF(t + 11);
        VSTEP(eE, t + 4); eE = EPF(t + 12);
        VSTEP(eF, t + 5); eF = EPF(t + 13);
        VSTEP(eG, t + 6); eG = EPF(t + 14);
        VSTEP(eH, t + 7); eH = EPF(t + 15);
    }
    for (; t < len; ++t) {
        VSTEP(eA, t);
        eA = eB; eB = eC; eC = eD; eD = eE; eE = eF; eF = eG; eG = eH;
    }

    score += endT[j];
    float bm = -__builtin_inff();
    int bt = 0;
#pragma unroll
    for (int i = 0; i < KK; ++i) {
        const float si = RLANE(i);
        if (si > bm) { bm = si; bt = i; }
    }
    if (j == 0) btarr[b] = bt;
}

// ---------------- hist recompute: tournament argmax (r3-validated semantics) ----------------
__global__ __launch_bounds__(256)
void hist_kernel(const float* __restrict__ em, const void* __restrict__ maskp,
                 const float* __restrict__ trans, const float* __restrict__ shist,
                 uchar* __restrict__ histg)
{
    const int tid = threadIdx.x;
    const int bid = blockIdx.x;
    const int b = bid >> 6;
    const int t0 = (bid & 63) * 8;

    __shared__ float tl[64][65];
    __shared__ float srow[8][64];

    const uchar* m8 = (const uchar*)maskp;
    const int* m32 = (const int*)maskp;
    const bool u8m = (m8[1] != 0);

#pragma unroll
    for (int p = 0; p < 16; ++p) {
        const int idx = p * 256 + tid;
        tl[idx >> 6][idx & 63] = trans[idx];
    }
#pragma unroll
    for (int p = 0; p < 2; ++p) {
        const int idx = p * 256 + tid;
        const int r = idx >> 6, i2 = idx & 63;
        const int ts = t0 - 1 + r;
        srow[r][i2] = (ts >= 0) ? shist[((size_t)b * TT + ts) * KK + i2] : 0.f;
    }
    __syncthreads();

    const int j = tid & 63;
    const int tq = tid >> 6;

#pragma unroll
    for (int half = 0; half < 2; ++half) {
        const int toff = tq * 2 + half;
        const int t = t0 + toff;
        if (t == 0) continue;
        const int mt = u8m ? (int)m8[b * TT + t] : m32[b * TT + t];
        uchar hv;
        if (!mt) {
            hv = (uchar)j;
        } else {
            const float e = em[((size_t)b * TT + t) * KK + j];
            const float* sr = &srow[toff][0];
            // chunk-8 contiguous-pair tournament; left-wins on >= => first-index
            float cv[8]; int ci[8];
#pragma unroll
            for (int c = 0; c < 8; ++c) {
                float tv[8]; int ti[8];
#pragma unroll
                for (int q = 0; q < 8; ++q) {
                    const int i = c * 8 + q;
                    tv[q] = (sr[i] + tl[i][j]) + e;   // reference order
                    ti[q] = i;
                }
#pragma unroll
                for (int n = 4; n >= 1; n >>= 1)
#pragma unroll
                    for (int q = 0; q < n; ++q) {
                        const bool g = tv[2 * q] >= tv[2 * q + 1];
                        tv[q] = g ? tv[2 * q] : tv[2 * q + 1];
                        ti[q] = g ? ti[2 * q] : ti[2 * q + 1];
                    }
                cv[c] = tv[0]; ci[c] = ti[0];
            }
#pragma unroll
            for (int n = 4; n >= 1; n >>= 1)
#pragma unroll
                for (int q = 0; q < n; ++q) {
                    const bool g = cv[2 * q] >= cv[2 * q + 1];
                    cv[q] = g ? cv[2 * q] : cv[2 * q + 1];
                    ci[q] = g ? ci[2 * q] : ci[2 * q + 1];
                }
            hv = (uchar)ci[0];
        }
        histg[((size_t)b * TT + t) * KK + j] = hv;
    }
}

// ---------------- Backtrack (validated r8-r20) ----------------
__global__ __launch_bounds__(256)
void viterbi_bt(const uchar* __restrict__ histg, const int* __restrict__ btarr,
                float* __restrict__ pred)
{
    const int b = blockIdx.x;
    const int tid = threadIdx.x;
    const int w = tid >> 6;
    const int j = tid & 63;

    __shared__ uchar hist[TT][KK];
    __shared__ uchar hypo[8][64][64];

    const uint4* src = (const uint4*)(histg + (size_t)b * TT * KK);
    uint4* dst = (uint4*)&hist[0][0];
#pragma unroll
    for (int p = 0; p < 8; ++p) dst[p * 256 + tid] = src[p * 256 + tid];
    __syncthreads();

    const int bt = btarr[b];

#pragma unroll
    for (int ss = 0; ss < 2; ++ss) {
        const int s = w * 2 + ss;
        int tag = j;
        if (s == 7) {
            hypo[7][63][j] = (uchar)j;
            for (int t = TT - 1; t >= 7 * 64 + 1; --t) {
                tag = hist[t][tag];
                hypo[7][t - 1 - 7 * 64][j] = (uchar)tag;
            }
        } else {
            for (int t = (s + 1) * 64; t >= s * 64 + 1; --t) {
                tag = hist[t][tag];
                hypo[s][t - 1 - s * 64][j] = (uchar)tag;
            }
        }
    }
    __syncthreads();

    int rows_[8];
    rows_[7] = bt;
#pragma unroll
    for (int s = 6; s >= 0; --s) rows_[s] = hypo[s + 1][0][rows_[s + 1]];

    float* pb = pred + (size_t)b * TT;
#pragma unroll
    for (int ss = 0; ss < 2; ++ss) {
        const int s = w * 2 + ss;
        pb[s * 64 + j] = (float)hypo[s][j][rows_[s]];
    }
}

// ---------------- Fallback monolithic viterbi (round-6, proven) ----------------
__global__ __launch_bounds__(256)
void viterbi_kernel(const float* __restrict__ em, const void* __restrict__ maskp,
                    const float* __restrict__ startT, const float* __restrict__ endT,
                    const float* __restrict__ trans, float* __restrict__ pred)
{
    const int b = blockIdx.x;
    const int tid = threadIdx.x;
    const int w = tid >> 6;
    const int j = tid & 63;

    __shared__ uchar hist[TT][KK];
    __shared__ uchar hypo[8][64][64];
    __shared__ int bt_sh;

    const uchar* m8 = (const uchar*)maskp;
    const int* m32 = (const int*)maskp;
    const bool u8m = (m8[1] != 0);

    if (w == 0) {
        float tc[KK];
#pragma unroll
        for (int i = 0; i < KK; ++i) tc[i] = trans[i * KK + j];

        const float* emb = em + (size_t)b * TT * KK;
        float score = startT[j] + emb[j];
        const float endv = endT[j];

        float e_cur = emb[KK + j];
        int   m_cur = u8m ? (int)m8[b * TT + 1] : m32[b * TT + 1];

        int t = 1;
        for (; t < TT; ++t) {
            const int tn2 = (t + 1 < TT) ? (t + 1) : (TT - 1);
            const float e_next = emb[(size_t)tn2 * KK + j];
            const int   m_next = u8m ? (int)m8[b * TT + tn2] : m32[b * TT + tn2];
            if (!m_cur) break;
            float m = -__builtin_inff();
            int idx = 0;
#pragma unroll
            for (int i = 0; i < KK; ++i) {
                const float si = __uint_as_float(__builtin_amdgcn_readlane(__float_as_uint(score), i));
                const float v = (si + tc[i]) + e_cur;
                if (v > m) { m = v; idx = i; }
            }
            score = m;
            hist[t][j] = (uchar)idx;
            e_cur = e_next; m_cur = m_next;
        }
        for (; t < TT; ++t) hist[t][j] = (uchar)j;

        score += endv;
        float bm = -__builtin_inff();
        int bt = 0;
#pragma unroll
        for (int i = 0; i < KK; ++i) {
            const float si = __uint_as_float(__builtin_amdgcn_readlane(__float_as_uint(score), i));
            if (si > bm) { bm = si; bt = i; }
        }
        if (j == 0) bt_sh = bt;
    }
    __syncthreads();

#pragma unroll
    for (int ss = 0; ss < 2; ++ss) {
        const int s = w * 2 + ss;
        int tag = j;
        if (s == 7) {
            hypo[7][63][j] = (uchar)j;
            for (int t = TT - 1; t >= 7 * 64 + 1; --t) {
                tag = hist[t][tag];
                hypo[7][t - 1 - 7 * 64][j] = (uchar)tag;
            }
        } else {
            for (int t = (s + 1) * 64; t >= s * 64 + 1; --t) {
                tag = hist[t][tag];
                hypo[s][t - 1 - s * 64][j] = (uchar)tag;
            }
        }
    }
    __syncthreads();

    const int bt = bt_sh;
    int rows_[8];
    rows_[7] = bt;
#pragma unroll
    for (int s = 6; s >= 0; --s) rows_[s] = hypo[s + 1][0][rows_[s + 1]];

    float* pb = pred + (size_t)b * TT;
#pragma unroll
    for (int ss = 0; ss < 2; ++ss) {
        const int s = w * 2 + ss;
        pb[s * 64 + j] = (float)hypo[s][j][rows_[s]];
    }
}

extern "C" void kernel_launch(void* const* d_in, const int* in_sizes, int n_in,
                              void* d_out, int out_size, void* d_ws, size_t ws_size,
                              hipStream_t stream) {
    const float* X      = (const float*)d_in[0];
    const void*  mask   = d_in[1];
    const float* W      = (const float*)d_in[2];
    const float* bias   = (const float*)d_in[3];
    const float* startT = (const float*)d_in[4];
    const float* endT   = (const float*)d_in[5];
    const float* trans  = (const float*)d_in[6];

    float* em   = (float*)d_out;
    float* pred = (float*)d_out + EMSZ;

    const size_t SH_BYTES = EMSZ * sizeof(float);          // 8 MB
    const size_t HI_BYTES = EMSZ;                          // 2 MB
    const size_t NEED  = SH_BYTES + HI_BYTES + 256;
    const size_t P_OFF = NEED;
    const size_t NEED3 = P_OFF + 4 * EMSZ * sizeof(float); // + 32 MB

    if (ws_size >= NEED) {
        float* shist = (float*)d_ws;
        uchar* histg = (uchar*)d_ws + SH_BYTES;
        int*   btarr = (int*)((uchar*)d_ws + SH_BYTES + HI_BYTES);

        if (ws_size >= NEED3) {
            float* part = (float*)((uchar*)d_ws + P_OFF);
            emission3_kernel<<<512, 256, 0, stream>>>(X, W, part);
            emadd_kernel<<<(int)(EMSZ / 4 / 256), 256, 0, stream>>>(part, bias, em);
        } else {
            emission_kernel<<<(BB * TT) / BM, 256, 0, stream>>>(X, W, bias, em);
        }
        viterbi_fwd<<<BB, 64, 0, stream>>>(em, mask, startT, endT, trans, shist, btarr);
        hist_kernel<<<BB * 64, 256, 0, stream>>>(em, mask, trans, shist, histg);
        viterbi_bt<<<BB, 256, 0, stream>>>(histg, btarr, pred);
    } else {
        emission_kernel<<<(BB * TT) / BM, 256, 0, stream>>>(X, W, bias, em);
        viterbi_kernel<<<BB, 256, 0, stream>>>(em, mask, startT, endT, trans, pred);
    }
}

// Round 22
// 197.451 us; speedup vs baseline: 1.1198x; 1.1198x over previous
//
#include <hip/hip_runtime.h>
#include <hip/hip_bf16.h>

#define BB 64
#define TT 512
#define FF 1024
#define KK 64
#define EMSZ ((size_t)BB * TT * KK)

typedef unsigned char uchar;
typedef float float2v __attribute__((ext_vector_type(2)));

// ---------------- Emission v3: 8x8 microtile, f-split x4 (r20, ~51us) ----------------
#define E3T 32
#define E3PA 260
#define E3PB 68

__global__ __launch_bounds__(256)
void emission3_kernel(const float* __restrict__ X, const float* __restrict__ W,
                      float* __restrict__ part)
{
    __shared__ float As[E3T][E3PA];
    __shared__ float Bs[E3T][E3PB];
    const int tid = threadIdx.x;
    const int bid = blockIdx.x;
    const int fs = bid & 3;
    const int rb = bid >> 2;
    const int row0 = rb * 256;
    const int fb = fs * 256;
    const int rg = tid >> 3;
    const int cg = tid & 7;
    const int r_base = rg * 8;
    const int c_base = cg * 8;

    float acc[8][8];
#pragma unroll
    for (int i = 0; i < 8; ++i)
#pragma unroll
        for (int j = 0; j < 8; ++j) acc[i][j] = 0.f;

    for (int ft = 0; ft < 256; ft += E3T) {
#pragma unroll
        for (int p = 0; p < 8; ++p) {
            const int idx = p * 256 + tid;
            const int row = idx >> 3;
            const int fq = idx & 7;
            const float4 a = *(const float4*)(X + (size_t)(row0 + row) * FF + fb + ft + fq * 4);
            As[fq * 4 + 0][row] = a.x;
            As[fq * 4 + 1][row] = a.y;
            As[fq * 4 + 2][row] = a.z;
            As[fq * 4 + 3][row] = a.w;
        }
#pragma unroll
        for (int p = 0; p < 2; ++p) {
            const int idx = p * 256 + tid;
            const int c = idx >> 3;
            const int fq = idx & 7;
            const float4 w = *(const float4*)(W + (size_t)c * FF + fb + ft + fq * 4);
            Bs[fq * 4 + 0][c] = w.x;
            Bs[fq * 4 + 1][c] = w.y;
            Bs[fq * 4 + 2][c] = w.z;
            Bs[fq * 4 + 3][c] = w.w;
        }
        __syncthreads();
#pragma unroll
        for (int f = 0; f < E3T; ++f) {
            const float4 a0 = *(const float4*)&As[f][r_base];
            const float4 a1 = *(const float4*)&As[f][r_base + 4];
            const float4 b0 = *(const float4*)&Bs[f][c_base];
            const float4 b1 = *(const float4*)&Bs[f][c_base + 4];
            const float av[8] = { a0.x, a0.y, a0.z, a0.w, a1.x, a1.y, a1.z, a1.w };
            const float bv[8] = { b0.x, b0.y, b0.z, b0.w, b1.x, b1.y, b1.z, b1.w };
#pragma unroll
            for (int i = 0; i < 8; ++i)
#pragma unroll
                for (int j = 0; j < 8; ++j)
                    acc[i][j] = fmaf(av[i], bv[j], acc[i][j]);
        }
        __syncthreads();
    }

    float* pp = part + (size_t)fs * EMSZ;
#pragma unroll
    for (int i = 0; i < 8; ++i) {
        float4 o0, o1;
        o0.x = acc[i][0]; o0.y = acc[i][1]; o0.z = acc[i][2]; o0.w = acc[i][3];
        o1.x = acc[i][4]; o1.y = acc[i][5]; o1.z = acc[i][6]; o1.w = acc[i][7];
        float* op = pp + (size_t)(row0 + r_base + i) * KK + c_base;
        *(float4*)(op + 0) = o0;
        *(float4*)(op + 4) = o1;
    }
}

__global__ __launch_bounds__(256)
void emadd_kernel(const float* __restrict__ part, const float* __restrict__ bias,
                  float* __restrict__ em)
{
    const size_t i = (size_t)blockIdx.x * 256 + threadIdx.x;
    const float4* p0 = (const float4*)part;
    const float4* p1 = (const float4*)(part + EMSZ);
    const float4* p2 = (const float4*)(part + 2 * EMSZ);
    const float4* p3 = (const float4*)(part + 3 * EMSZ);
    const float4 a = p0[i], b = p1[i], c = p2[i], d = p3[i];
    const float4 bv = *(const float4*)(bias + ((int)(i & 15)) * 4);
    float4 o;
    o.x = (((a.x + b.x) + c.x) + d.x) + bv.x;
    o.y = (((a.y + b.y) + c.y) + d.y) + bv.y;
    o.z = (((a.z + b.z) + c.z) + d.z) + bv.z;
    o.w = (((a.w + b.w) + c.w) + d.w) + bv.w;
    ((float4*)em)[i] = o;
}

// ---------------- Emission v1 (fallback, measured ~84us 7x) ----------------
#define BM 64
#define BF 64
#define LDA 68

__global__ __launch_bounds__(256)
void emission_kernel(const float* __restrict__ X, const float* __restrict__ W,
                     const float* __restrict__ bias, float* __restrict__ em)
{
    __shared__ float As[BF][LDA];
    __shared__ float Bs[BF][LDA];
    const int tid = threadIdx.x;
    const int row0 = blockIdx.x * BM;
    const int tm = tid & 15;
    const int tn = tid >> 4;
    const int lq = tid & 15;
    const int lr = tid >> 4;

    float acc[4][4];
#pragma unroll
    for (int i = 0; i < 4; ++i)
#pragma unroll
        for (int jj = 0; jj < 4; ++jj) acc[i][jj] = 0.f;

    for (int f0 = 0; f0 < FF; f0 += BF) {
#pragma unroll
        for (int p = 0; p < 4; ++p) {
            const int r = p * 16 + lr;
            float4 a = *(const float4*)(X + (size_t)(row0 + r) * FF + f0 + lq * 4);
            As[lq * 4 + 0][r] = a.x;
            As[lq * 4 + 1][r] = a.y;
            As[lq * 4 + 2][r] = a.z;
            As[lq * 4 + 3][r] = a.w;
            float4 w = *(const float4*)(W + (size_t)r * FF + f0 + lq * 4);
            Bs[lq * 4 + 0][r] = w.x;
            Bs[lq * 4 + 1][r] = w.y;
            Bs[lq * 4 + 2][r] = w.z;
            Bs[lq * 4 + 3][r] = w.w;
        }
        __syncthreads();
#pragma unroll
        for (int f = 0; f < BF; ++f) {
            float4 a = *(const float4*)&As[f][tm * 4];
            float4 b = *(const float4*)&Bs[f][tn * 4];
            acc[0][0] += a.x * b.x; acc[0][1] += a.x * b.y; acc[0][2] += a.x * b.z; acc[0][3] += a.x * b.w;
            acc[1][0] += a.y * b.x; acc[1][1] += a.y * b.y; acc[1][2] += a.y * b.z; acc[1][3] += a.y * b.w;
            acc[2][0] += a.z * b.x; acc[2][1] += a.z * b.y; acc[2][2] += a.z * b.z; acc[2][3] += a.z * b.w;
            acc[3][0] += a.w * b.x; acc[3][1] += a.w * b.y; acc[3][2] += a.w * b.z; acc[3][3] += a.w * b.w;
        }
        __syncthreads();
    }

    const float4 b4 = *(const float4*)(bias + tn * 4);
#pragma unroll
    for (int i = 0; i < 4; ++i) {
        float4 o;
        o.x = acc[i][0] + b4.x;
        o.y = acc[i][1] + b4.y;
        o.z = acc[i][2] + b4.z;
        o.w = acc[i][3] + b4.w;
        *(float4*)(em + (size_t)(row0 + tm * 4 + i) * KK + tn * 4) = o;
    }
}

// ---------------- Forward: value-only, LDS-broadcast + packed adds, unroll-8 (r21) ----------------
#define VSTEP(EV, TIDX) do {                                                   \
    const float2v* sp2 = (const float2v*)&sbuf[(TIDX) & 1][0];                 \
    float m_;                                                                  \
    _Pragma("unroll")                                                          \
    for (int c = 0; c < 8; ++c) {                                              \
        const float2v p0 = sp2[c * 4 + 0] + tc2[c * 4 + 0];                    \
        const float2v p1 = sp2[c * 4 + 1] + tc2[c * 4 + 1];                    \
        const float2v p2 = sp2[c * 4 + 2] + tc2[c * 4 + 2];                    \
        const float2v p3 = sp2[c * 4 + 3] + tc2[c * 4 + 3];                    \
        const float ma = fmaxf(fmaxf(p0.x, p0.y), p1.x);   /* v_max3 */        \
        const float mb = fmaxf(fmaxf(p1.y, p2.x), p2.y);                       \
        const float mc = fmaxf(fmaxf(p3.x, p3.y), ma);                         \
        const float w_ = fmaxf(mb, mc);                                        \
        m_ = (c == 0) ? w_ : fmaxf(m_, w_);                                    \
    }                                                                          \
    score = m_ + (EV);                                                         \
    sbuf[((TIDX) + 1) & 1][j] = score;                                         \
    sb[(size_t)(TIDX) * KK + j] = score;                                       \
} while (0)

#define EPF(D) emb[(size_t)(((D) < TT) ? (D) : (TT - 1)) * KK + j]
#define RLANE(I) __uint_as_float((unsigned)__builtin_amdgcn_readlane((int)__float_as_uint(score), (I)))

__global__ __launch_bounds__(64)
__attribute__((amdgpu_waves_per_eu(1, 1)))
void viterbi_fwd(const float* __restrict__ em, const void* __restrict__ maskp,
                 const float* __restrict__ startT, const float* __restrict__ endT,
                 const float* __restrict__ trans, float* __restrict__ shist,
                 int* __restrict__ btarr)
{
    __shared__ float sbuf[2][KK];

    const int b = blockIdx.x;
    const int j = threadIdx.x;

    const uchar* m8 = (const uchar*)maskp;
    const int* m32 = (const int*)maskp;
    const bool u8m = (m8[1] != 0);

    int myc;
    if (u8m) {
        const uint2 mv = *(const uint2*)(m8 + (size_t)b * TT + j * 8);
        const unsigned s4 = (mv.x & 0x01010101u) + (mv.y & 0x01010101u);
        myc = (int)((s4 * 0x01010101u) >> 24);
    } else {
        const int* mp = m32 + (size_t)b * TT + j * 8;
        const int4 a = *(const int4*)mp;
        const int4 c = *(const int4*)(mp + 4);
        myc = (a.x != 0) + (a.y != 0) + (a.z != 0) + (a.w != 0)
            + (c.x != 0) + (c.y != 0) + (c.z != 0) + (c.w != 0);
    }
#pragma unroll
    for (int o = 1; o < 64; o <<= 1) myc += __shfl_xor(myc, o, 64);
    const int len = myc;

    float2v tc2[32];
#pragma unroll
    for (int i = 0; i < 32; ++i) {
        tc2[i].x = trans[(2 * i) * KK + j];
        tc2[i].y = trans[(2 * i + 1) * KK + j];
    }
#pragma unroll
    for (int i = 0; i < 32; ++i) asm volatile("" : "+v"(tc2[i]));

    const float* emb = em + (size_t)b * TT * KK;
    float* sb = shist + (size_t)b * TT * KK;

    float score = startT[j] + emb[j];
    sb[j] = score;
    sbuf[1][j] = score;

    float eA = EPF(1), eB = EPF(2), eC = EPF(3), eD = EPF(4);
    float eE = EPF(5), eF = EPF(6), eG = EPF(7), eH = EPF(8);

    int t = 1;
    for (; t + 7 < len; t += 8) {
        VSTEP(eA, t);     eA = EPF(t + 8);
        VSTEP(eB, t + 1); eB = EPF(t + 9);
        VSTEP(eC, t + 2); eC = EPF(t + 10);
        VSTEP(eD, t + 3); eD = EPF(t + 11);
        VSTEP(eE, t + 4); eE = EPF(t + 12);
        VSTEP(eF, t + 5); eF = EPF(t + 13);
        VSTEP(eG, t + 6); eG = EPF(t + 14);
        VSTEP(eH, t + 7); eH = EPF(t + 15);
    }
    for (; t < len; ++t) {
        VSTEP(eA, t);
        eA = eB; eB = eC; eC = eD; eD = eE; eE = eF; eF = eG; eG = eH;
    }

    score += endT[j];
    float bm = -__builtin_inff();
    int bt = 0;
#pragma unroll
    for (int i = 0; i < KK; ++i) {
        const float si = RLANE(i);
        if (si > bm) { bm = si; bt = i; }
    }
    if (j == 0) btarr[b] = bt;
}

// ---------------- hist recompute: serial chain (r8-r20 proven, ~15us) ----------------
__global__ __launch_bounds__(256)
void hist_kernel(const float* __restrict__ em, const void* __restrict__ maskp,
                 const float* __restrict__ trans, const float* __restrict__ shist,
                 uchar* __restrict__ histg)
{
    const int tid = threadIdx.x;
    const int bid = blockIdx.x;
    const int b = bid >> 6;
    const int t0 = (bid & 63) * 8;

    __shared__ float tl[64][65];
    __shared__ float srow[8][64];

    const uchar* m8 = (const uchar*)maskp;
    const int* m32 = (const int*)maskp;
    const bool u8m = (m8[1] != 0);

#pragma unroll
    for (int p = 0; p < 16; ++p) {
        const int idx = p * 256 + tid;
        tl[idx >> 6][idx & 63] = trans[idx];
    }
#pragma unroll
    for (int p = 0; p < 2; ++p) {
        const int idx = p * 256 + tid;
        const int r = idx >> 6, i2 = idx & 63;
        const int ts = t0 - 1 + r;
        srow[r][i2] = (ts >= 0) ? shist[((size_t)b * TT + ts) * KK + i2] : 0.f;
    }
    __syncthreads();

    const int j = tid & 63;
    const int tq = tid >> 6;

#pragma unroll
    for (int half = 0; half < 2; ++half) {
        const int toff = tq * 2 + half;
        const int t = t0 + toff;
        if (t == 0) continue;
        const int mt = u8m ? (int)m8[b * TT + t] : m32[b * TT + t];
        uchar hv;
        if (!mt) {
            hv = (uchar)j;
        } else {
            const float e = em[((size_t)b * TT + t) * KK + j];
            const float* sr = &srow[toff][0];
            float bm = -__builtin_inff();
            int bi = 0;
#pragma unroll 16
            for (int i = 0; i < KK; ++i) {
                const float cand = (sr[i] + tl[i][j]) + e;   // reference order
                if (cand > bm) { bm = cand; bi = i; }        // strict >: first index
            }
            hv = (uchar)bi;
        }
        histg[((size_t)b * TT + t) * KK + j] = hv;
    }
}

// ---------------- Backtrack (validated r8-r21) ----------------
__global__ __launch_bounds__(256)
void viterbi_bt(const uchar* __restrict__ histg, const int* __restrict__ btarr,
                float* __restrict__ pred)
{
    const int b = blockIdx.x;
    const int tid = threadIdx.x;
    const int w = tid >> 6;
    const int j = tid & 63;

    __shared__ uchar hist[TT][KK];
    __shared__ uchar hypo[8][64][64];

    const uint4* src = (const uint4*)(histg + (size_t)b * TT * KK);
    uint4* dst = (uint4*)&hist[0][0];
#pragma unroll
    for (int p = 0; p < 8; ++p) dst[p * 256 + tid] = src[p * 256 + tid];
    __syncthreads();

    const int bt = btarr[b];

#pragma unroll
    for (int ss = 0; ss < 2; ++ss) {
        const int s = w * 2 + ss;
        int tag = j;
        if (s == 7) {
            hypo[7][63][j] = (uchar)j;
            for (int t = TT - 1; t >= 7 * 64 + 1; --t) {
                tag = hist[t][tag];
                hypo[7][t - 1 - 7 * 64][j] = (uchar)tag;
            }
        } else {
            for (int t = (s + 1) * 64; t >= s * 64 + 1; --t) {
                tag = hist[t][tag];
                hypo[s][t - 1 - s * 64][j] = (uchar)tag;
            }
        }
    }
    __syncthreads();

    int rows_[8];
    rows_[7] = bt;
#pragma unroll
    for (int s = 6; s >= 0; --s) rows_[s] = hypo[s + 1][0][rows_[s + 1]];

    float* pb = pred + (size_t)b * TT;
#pragma unroll
    for (int ss = 0; ss < 2; ++ss) {
        const int s = w * 2 + ss;
        pb[s * 64 + j] = (float)hypo[s][j][rows_[s]];
    }
}

// ---------------- Fallback monolithic viterbi (round-6, proven) ----------------
__global__ __launch_bounds__(256)
void viterbi_kernel(const float* __restrict__ em, const void* __restrict__ maskp,
                    const float* __restrict__ startT, const float* __restrict__ endT,
                    const float* __restrict__ trans, float* __restrict__ pred)
{
    const int b = blockIdx.x;
    const int tid = threadIdx.x;
    const int w = tid >> 6;
    const int j = tid & 63;

    __shared__ uchar hist[TT][KK];
    __shared__ uchar hypo[8][64][64];
    __shared__ int bt_sh;

    const uchar* m8 = (const uchar*)maskp;
    const int* m32 = (const int*)maskp;
    const bool u8m = (m8[1] != 0);

    if (w == 0) {
        float tc[KK];
#pragma unroll
        for (int i = 0; i < KK; ++i) tc[i] = trans[i * KK + j];

        const float* emb = em + (size_t)b * TT * KK;
        float score = startT[j] + emb[j];
        const float endv = endT[j];

        float e_cur = emb[KK + j];
        int   m_cur = u8m ? (int)m8[b * TT + 1] : m32[b * TT + 1];

        int t = 1;
        for (; t < TT; ++t) {
            const int tn2 = (t + 1 < TT) ? (t + 1) : (TT - 1);
            const float e_next = emb[(size_t)tn2 * KK + j];
            const int   m_next = u8m ? (int)m8[b * TT + tn2] : m32[b * TT + tn2];
            if (!m_cur) break;
            float m = -__builtin_inff();
            int idx = 0;
#pragma unroll
            for (int i = 0; i < KK; ++i) {
                const float si = __uint_as_float(__builtin_amdgcn_readlane(__float_as_uint(score), i));
                const float v = (si + tc[i]) + e_cur;
                if (v > m) { m = v; idx = i; }
            }
            score = m;
            hist[t][j] = (uchar)idx;
            e_cur = e_next; m_cur = m_next;
        }
        for (; t < TT; ++t) hist[t][j] = (uchar)j;

        score += endv;
        float bm = -__builtin_inff();
        int bt = 0;
#pragma unroll
        for (int i = 0; i < KK; ++i) {
            const float si = __uint_as_float(__builtin_amdgcn_readlane(__float_as_uint(score), i));
            if (si > bm) { bm = si; bt = i; }
        }
        if (j == 0) bt_sh = bt;
    }
    __syncthreads();

#pragma unroll
    for (int ss = 0; ss < 2; ++ss) {
        const int s = w * 2 + ss;
        int tag = j;
        if (s == 7) {
            hypo[7][63][j] = (uchar)j;
            for (int t = TT - 1; t >= 7 * 64 + 1; --t) {
                tag = hist[t][tag];
                hypo[7][t - 1 - 7 * 64][j] = (uchar)tag;
            }
        } else {
            for (int t = (s + 1) * 64; t >= s * 64 + 1; --t) {
                tag = hist[t][tag];
                hypo[s][t - 1 - s * 64][j] = (uchar)tag;
            }
        }
    }
    __syncthreads();

    const int bt = bt_sh;
    int rows_[8];
    rows_[7] = bt;
#pragma unroll
    for (int s = 6; s >= 0; --s) rows_[s] = hypo[s + 1][0][rows_[s + 1]];

    float* pb = pred + (size_t)b * TT;
#pragma unroll
    for (int ss = 0; ss < 2; ++ss) {
        const int s = w * 2 + ss;
        pb[s * 64 + j] = (float)hypo[s][j][rows_[s]];
    }
}

extern "C" void kernel_launch(void* const* d_in, const int* in_sizes, int n_in,
                              void* d_out, int out_size, void* d_ws, size_t ws_size,
                              hipStream_t stream) {
    const float* X      = (const float*)d_in[0];
    const void*  mask   = d_in[1];
    const float* W      = (const float*)d_in[2];
    const float* bias   = (const float*)d_in[3];
    const float* startT = (const float*)d_in[4];
    const float* endT   = (const float*)d_in[5];
    const float* trans  = (const float*)d_in[6];

    float* em   = (float*)d_out;
    float* pred = (float*)d_out + EMSZ;

    const size_t SH_BYTES = EMSZ * sizeof(float);          // 8 MB
    const size_t HI_BYTES = EMSZ;                          // 2 MB
    const size_t NEED  = SH_BYTES + HI_BYTES + 256;
    const size_t P_OFF = NEED;
    const size_t NEED3 = P_OFF + 4 * EMSZ * sizeof(float); // + 32 MB

    if (ws_size >= NEED) {
        float* shist = (float*)d_ws;
        uchar* histg = (uchar*)d_ws + SH_BYTES;
        int*   btarr = (int*)((uchar*)d_ws + SH_BYTES + HI_BYTES);

        if (ws_size >= NEED3) {
            float* part = (float*)((uchar*)d_ws + P_OFF);
            emission3_kernel<<<512, 256, 0, stream>>>(X, W, part);
            emadd_kernel<<<(int)(EMSZ / 4 / 256), 256, 0, stream>>>(part, bias, em);
        } else {
            emission_kernel<<<(BB * TT) / BM, 256, 0, stream>>>(X, W, bias, em);
        }
        viterbi_fwd<<<BB, 64, 0, stream>>>(em, mask, startT, endT, trans, shist, btarr);
        hist_kernel<<<BB * 64, 256, 0, stream>>>(em, mask, trans, shist, histg);
        viterbi_bt<<<BB, 256, 0, stream>>>(histg, btarr, pred);
    } else {
        emission_kernel<<<(BB * TT) / BM, 256, 0, stream>>>(X, W, bias, em);
        viterbi_kernel<<<BB, 256, 0, stream>>>(em, mask, startT, endT, trans, pred);
    }
}